// Round 1
// baseline (280.160 us; speedup 1.0000x reference)
//
#include <hip/hip_runtime.h>
#include <hip/hip_bf16.h>
#include <math.h>

#define H_ 16
#define KC_ 16
#define ZD_ 64
#define HID_ 256
#define O_ 2048
#define NW2_ 49152                    // OC*IC*KW columns of W2
#define W2D_OUT 37748736              // O*I*KW*L
#define DPDE_ 64

typedef short bf16x8 __attribute__((ext_vector_type(8)));
typedef float f32x4 __attribute__((ext_vector_type(4)));

struct F3 { float x, y, z; };         // 12B, 4B-aligned -> dwordx3

static __device__ __forceinline__ unsigned short f2bf(float f) {
    union { float f; unsigned u; } v; v.f = f;
    unsigned r = v.u + 0x7FFF + ((v.u >> 16) & 1);   // RNE
    return (unsigned short)(r >> 16);
}

static __device__ __forceinline__ unsigned pack2(float lo, float hi) {
    return (unsigned)f2bf(lo) | ((unsigned)f2bf(hi) << 16);
}

// ---------------------------------------------------------------------------
// Prep: per-block redundant mean+feat (pde L2-cached), hidden in MFMA-A layout
// hiddenA[k>>3][m][k&7] bf16, plus bb for blocks 0..7.  grid 256 x 256.
// ---------------------------------------------------------------------------
__global__ void prep_kernel(const float* __restrict__ Z,
                            const float* __restrict__ pde,
                            const float* __restrict__ W1,
                            const float* __restrict__ U1,
                            const float* __restrict__ b1,
                            const float* __restrict__ z_bias,
                            const float* __restrict__ u_bias,
                            unsigned short* __restrict__ hiddenA,
                            float* __restrict__ out_bb) {
    __shared__ float part[16][64];
    __shared__ float meanv[64];
    __shared__ float zr[64];
    const int t = threadIdx.x, m = blockIdx.x;
    if (t < 64) zr[t] = Z[m * ZD_ + t];
    const int c4 = t & 15, rg = t >> 4;
    float sx = 0.f, sy = 0.f, sz = 0.f, sw = 0.f;
    const float4* p = (const float4*)pde;      // 16 float4 per 64-col row
    for (int r = 0; r < 64; ++r) {
        float4 v = p[(rg * 64 + r) * 16 + c4];
        sx += v.x; sy += v.y; sz += v.z; sw += v.w;
    }
    part[rg][c4 * 4 + 0] = sx; part[rg][c4 * 4 + 1] = sy;
    part[rg][c4 * 4 + 2] = sz; part[rg][c4 * 4 + 3] = sw;
    __syncthreads();
    if (t < 64) {
        float a = 0.f;
        #pragma unroll
        for (int g = 0; g < 16; ++g) a += part[g][t];
        meanv[t] = a * (1.f / 1024.f);
    }
    __syncthreads();
    float f = b1[t];
    #pragma unroll
    for (int d = 0; d < 64; ++d) f = fmaf(meanv[d], U1[d * HID_ + t], f);
    float s = f;
    #pragma unroll
    for (int d = 0; d < 64; ++d) s = fmaf(zr[d], W1[d * HID_ + t], s);
    // MFMA-A-native layout: hiddenA[(k/8)*256 + m][k%8]
    hiddenA[((size_t)(t >> 3) * 256 + m) * 8 + (t & 7)] = f2bf(tanhf(s));
    if (m < 8) {
        const int idx = m * 256 + t;
        out_bb[idx] = z_bias[idx] + u_bias[idx];
    }
}

// ---------------------------------------------------------------------------
// Fused MFMA GEMM + expansion, single-fetch W2, single-barrier staging.
// grid 512: block -> oc = b>>2 (0..127), icq = b&3.  512 threads = 8 waves.
// Block: all m (256 rows) x 96 n-cols (n0g = oc*384 + icq*96), k = 256.
//
// LDS bT: transposed W2 strip, k-pairs packed as dwords, XOR-swizzled:
//   row n (0..95), dword index kpx = kp ^ ((nq&7)<<1) ^ (((nq>>3)&1)<<4),
//   nq = n>>2, kp = k>>1 (dword = bf16(k=2kp) | bf16(k=2kp+1)<<16).
// Write instr: 24-lane k-row groups spread over 16 banks (<=2-way, free)
// instead of the old 2-bank 12-way ds_write_u16 storm.
// Read: two ds_read_b64 per 8-k fragment, same involution -> contiguous.
// ---------------------------------------------------------------------------
#define BT_S2 132                     // row stride in DWORDS (528B, breaks read aliasing)

__global__ __launch_bounds__(512, 4)
void gemm_expand(const unsigned short* __restrict__ hiddenA,
                 const float* __restrict__ W2,
                 const float* __restrict__ b2,
                 const float* __restrict__ unet,
                 float* __restrict__ out) {
    __shared__ unsigned bT[96 * BT_S2];        // 50688 B

    const int t = threadIdx.x;
    const int lane = t & 63;
    const int wave = t >> 6;                  // 0..7
    const int n15 = lane & 15;
    const int quad = lane >> 4;
    const int oc = blockIdx.x >> 2;
    const int icq = blockIdx.x & 3;
    const int n0g = oc * 384 + icq * 96;

    // ---- stage ALL K=256 x 96n of W2, k-pair packed bf16, one pass ----
    #pragma unroll
    for (int i = 0; i < 6; ++i) {
        const int u  = i * 512 + t;           // 0..3071 units
        const int kp = u / 24;                // 0..127 -> k = 2kp, 2kp+1
        const int nq = u - kp * 24;           // 0..23  -> n = 4nq..4nq+3
        const float* p0 = W2 + (size_t)(2 * kp) * NW2_ + n0g + nq * 4;
        const float4 va = *(const float4*)p0;          // row k=2kp
        const float4 vb = *(const float4*)(p0 + NW2_); // row k=2kp+1
        const int kpx = kp ^ ((nq & 7) << 1) ^ (((nq >> 3) & 1) << 4);
        unsigned* r0 = &bT[(4 * nq) * BT_S2 + kpx];
        r0[0 * BT_S2] = pack2(va.x, vb.x);
        r0[1 * BT_S2] = pack2(va.y, vb.y);
        r0[2 * BT_S2] = pack2(va.z, vb.z);
        r0[3 * BT_S2] = pack2(va.w, vb.w);
    }
    __syncthreads();

    f32x4 acc[2][6];
    #pragma unroll
    for (int a = 0; a < 2; ++a)
        #pragma unroll
        for (int b = 0; b < 6; ++b) acc[a][b] = (f32x4){0.f, 0.f, 0.f, 0.f};

    // ---- MFMA: 8 k-steps of 32, no further barriers ----
    #pragma unroll
    for (int ks = 0; ks < 8; ++ks) {
        const int g = ks * 4 + quad;          // 8-k group index 0..31
        bf16x8 afr[2];
        #pragma unroll
        for (int mi = 0; mi < 2; ++mi)
            afr[mi] = *(const bf16x8*)(hiddenA +
                      ((size_t)g * 256 + (wave * 2 + mi) * 16 + n15) * 8);
        const int base4 = ks * 16 + quad * 4; // kp base of this 8-k fragment
        #pragma unroll
        for (int nt = 0; nt < 6; ++nt) {
            const int n = nt * 16 + n15;
            const int nqr = n >> 2;
            const int swz = ((nqr & 7) << 1) ^ (((nqr >> 3) & 1) << 4);
            const unsigned* row = &bT[n * BT_S2];
            union { bf16x8 v; unsigned long long q[2]; } bb;
            bb.q[0] = *(const unsigned long long*)&row[(base4)     ^ swz];
            bb.q[1] = *(const unsigned long long*)&row[(base4 + 2) ^ swz];
            acc[0][nt] = __builtin_amdgcn_mfma_f32_16x16x32_bf16(afr[0], bb.v, acc[0][nt], 0, 0, 0);
            acc[1][nt] = __builtin_amdgcn_mfma_f32_16x16x32_bf16(afr[1], bb.v, acc[1][nt], 0, 0, 0);
        }
    }

    // ---- epilogue: out[o][i][kw][l] = (w + b2) * unet[o][i][l], dwordx3 I/O ----
    #pragma unroll
    for (int mi = 0; mi < 2; ++mi) {
        const int o = (wave * 2 + mi) * 128 + oc;
        const float* ub_o = unet + (size_t)o * 6144;
        float* ob_o = out + (size_t)o * 18432;
        #pragma unroll
        for (int nt = 0; nt < 6; ++nt) {
            const int nl = nt * 16 + n15;         // 0..95 (col within block strip)
            const int n_rel = icq * 96 + nl;      // 0..383 = ic*3 + kw
            const int ic = n_rel / 3;
            const float gb2 = b2[n0g + nl];
            #pragma unroll
            for (int r = 0; r < 4; ++r) {
                const int kc = quad * 4 + r;
                const float w = acc[mi][nt][r] + gb2;
                const F3 u = *(const F3*)(ub_o + kc * 384 + ic * 3);
                F3 res; res.x = w * u.x; res.y = w * u.y; res.z = w * u.z;
                *(F3*)(ob_o + kc * 1152 + n_rel * 3) = res;
            }
        }
    }
}

// ---------------------------------------------------------------------------
extern "C" void kernel_launch(void* const* d_in, const int* in_sizes, int n_in,
                              void* d_out, int out_size, void* d_ws, size_t ws_size,
                              hipStream_t stream) {
    const float* Z       = (const float*)d_in[0];
    const float* z_bias  = (const float*)d_in[1];
    const float* unet_w  = (const float*)d_in[2];
    const float* unet_b  = (const float*)d_in[3];
    const float* pde     = (const float*)d_in[4];
    const float* W1      = (const float*)d_in[5];
    const float* U1      = (const float*)d_in[6];
    const float* b1      = (const float*)d_in[7];
    const float* W2      = (const float*)d_in[8];
    const float* b2      = (const float*)d_in[9];
    float* out = (float*)d_out;

    unsigned short* hiddenA = (unsigned short*)d_ws;   // 256*256 bf16 = 128 KB

    prep_kernel<<<256, 256, 0, stream>>>(Z, pde, W1, U1, b1, z_bias, unet_b,
                                         hiddenA, out + W2D_OUT);
    gemm_expand<<<512, 512, 0, stream>>>(hiddenA, W2, b2, unet_w, out);
}

// Round 2
// 277.754 us; speedup vs baseline: 1.0087x; 1.0087x over previous
//
#include <hip/hip_runtime.h>
#include <hip/hip_bf16.h>
#include <math.h>

#define H_ 16
#define KC_ 16
#define ZD_ 64
#define HID_ 256
#define O_ 2048
#define NW2_ 49152                    // OC*IC*KW columns of W2
#define W2D_OUT 37748736              // O*I*KW*L
#define DPDE_ 64

typedef short bf16x8 __attribute__((ext_vector_type(8)));
typedef float f32x4 __attribute__((ext_vector_type(4)));

static __device__ __forceinline__ unsigned short f2bf(float f) {
    union { float f; unsigned u; } v; v.f = f;
    unsigned r = v.u + 0x7FFF + ((v.u >> 16) & 1);   // RNE
    return (unsigned short)(r >> 16);
}

static __device__ __forceinline__ unsigned pack2(float lo, float hi) {
    return (unsigned)f2bf(lo) | ((unsigned)f2bf(hi) << 16);
}

// ---------------------------------------------------------------------------
// Prep: per-block redundant mean+feat (pde L2-cached), hidden in MFMA-A layout
// hiddenA[k>>3][m][k&7] bf16, plus bb for blocks 0..7.  grid 256 x 256.
// ---------------------------------------------------------------------------
__global__ void prep_kernel(const float* __restrict__ Z,
                            const float* __restrict__ pde,
                            const float* __restrict__ W1,
                            const float* __restrict__ U1,
                            const float* __restrict__ b1,
                            const float* __restrict__ z_bias,
                            const float* __restrict__ u_bias,
                            unsigned short* __restrict__ hiddenA,
                            float* __restrict__ out_bb) {
    __shared__ float part[16][64];
    __shared__ float meanv[64];
    __shared__ float zr[64];
    const int t = threadIdx.x, m = blockIdx.x;
    if (t < 64) zr[t] = Z[m * ZD_ + t];
    const int c4 = t & 15, rg = t >> 4;
    float sx = 0.f, sy = 0.f, sz = 0.f, sw = 0.f;
    const float4* p = (const float4*)pde;      // 16 float4 per 64-col row
    for (int r = 0; r < 64; ++r) {
        float4 v = p[(rg * 64 + r) * 16 + c4];
        sx += v.x; sy += v.y; sz += v.z; sw += v.w;
    }
    part[rg][c4 * 4 + 0] = sx; part[rg][c4 * 4 + 1] = sy;
    part[rg][c4 * 4 + 2] = sz; part[rg][c4 * 4 + 3] = sw;
    __syncthreads();
    if (t < 64) {
        float a = 0.f;
        #pragma unroll
        for (int g = 0; g < 16; ++g) a += part[g][t];
        meanv[t] = a * (1.f / 1024.f);
    }
    __syncthreads();
    float f = b1[t];
    #pragma unroll
    for (int d = 0; d < 64; ++d) f = fmaf(meanv[d], U1[d * HID_ + t], f);
    float s = f;
    #pragma unroll
    for (int d = 0; d < 64; ++d) s = fmaf(zr[d], W1[d * HID_ + t], s);
    // MFMA-A-native layout: hiddenA[(k/8)*256 + m][k%8]
    hiddenA[((size_t)(t >> 3) * 256 + m) * 8 + (t & 7)] = f2bf(tanhf(s));
    if (m < 8) {
        const int idx = m * 256 + t;
        out_bb[idx] = z_bias[idx] + u_bias[idx];
    }
}

// ---------------------------------------------------------------------------
// Fused MFMA GEMM + expansion.
// grid 512: block -> oc = b>>2 (0..127), icq = b&3.  512 threads = 8 waves.
// Stage+MFMA identical to R1 (proven insensitive).  NEW epilogue:
//   1) per-wave w-tile (16 kc x 96 n, f32) bounced through wave-private LDS
//      (reuses bT storage; one barrier after MFMA protects the aliasing)
//   2) drain with lane-contiguous mapping: per (mi,kp,j) each 32-lane half
//      stores 128 B contiguous / 64 B aligned; 9 consecutive j's complete a
//      1152 B run per (o,kc).  unet dword read once per 3 outputs (L1).
// ---------------------------------------------------------------------------
#define BT_S2 132                     // staging row stride in DWORDS
#define WL_ST 97                      // w-tile row stride in dwords (pad +1)
#define WL_SZ 1552                    // 16*97 per wave

__global__ __launch_bounds__(512, 4)
void gemm_expand(const unsigned short* __restrict__ hiddenA,
                 const float* __restrict__ W2,
                 const float* __restrict__ b2,
                 const float* __restrict__ unet,
                 float* __restrict__ out) {
    __shared__ unsigned bT[96 * BT_S2];        // 50688 B (>= 8*WL_SZ*4 = 49664)

    const int t = threadIdx.x;
    const int lane = t & 63;
    const int wave = t >> 6;                  // 0..7
    const int n15 = lane & 15;
    const int quad = lane >> 4;
    const int L = lane & 31;
    const int half = lane >> 5;
    const int oc = blockIdx.x >> 2;
    const int icq = blockIdx.x & 3;
    const int n0g = oc * 384 + icq * 96;

    // ---- stage ALL K=256 x 96n of W2, k-pair packed bf16, one pass ----
    #pragma unroll
    for (int i = 0; i < 6; ++i) {
        const int u  = i * 512 + t;           // 0..3071 units
        const int kp = u / 24;                // 0..127 -> k = 2kp, 2kp+1
        const int nq = u - kp * 24;           // 0..23  -> n = 4nq..4nq+3
        const float* p0 = W2 + (size_t)(2 * kp) * NW2_ + n0g + nq * 4;
        const float4 va = *(const float4*)p0;          // row k=2kp
        const float4 vb = *(const float4*)(p0 + NW2_); // row k=2kp+1
        const int kpx = kp ^ ((nq & 7) << 1) ^ (((nq >> 3) & 1) << 4);
        unsigned* r0 = &bT[(4 * nq) * BT_S2 + kpx];
        r0[0 * BT_S2] = pack2(va.x, vb.x);
        r0[1 * BT_S2] = pack2(va.y, vb.y);
        r0[2 * BT_S2] = pack2(va.z, vb.z);
        r0[3 * BT_S2] = pack2(va.w, vb.w);
    }
    __syncthreads();

    f32x4 acc[2][6];
    #pragma unroll
    for (int a = 0; a < 2; ++a)
        #pragma unroll
        for (int b = 0; b < 6; ++b) acc[a][b] = (f32x4){0.f, 0.f, 0.f, 0.f};

    // ---- MFMA: 8 k-steps of 32, no barriers inside ----
    #pragma unroll
    for (int ks = 0; ks < 8; ++ks) {
        const int g = ks * 4 + quad;          // 8-k group index 0..31
        bf16x8 afr[2];
        #pragma unroll
        for (int mi = 0; mi < 2; ++mi)
            afr[mi] = *(const bf16x8*)(hiddenA +
                      ((size_t)g * 256 + (wave * 2 + mi) * 16 + n15) * 8);
        const int base4 = ks * 16 + quad * 4; // kp base of this 8-k fragment
        #pragma unroll
        for (int nt = 0; nt < 6; ++nt) {
            const int n = nt * 16 + n15;
            const int nqr = n >> 2;
            const int swz = ((nqr & 7) << 1) ^ (((nqr >> 3) & 1) << 4);
            const unsigned* row = &bT[n * BT_S2];
            union { bf16x8 v; unsigned long long q[2]; } bb;
            bb.q[0] = *(const unsigned long long*)&row[(base4)     ^ swz];
            bb.q[1] = *(const unsigned long long*)&row[(base4 + 2) ^ swz];
            acc[0][nt] = __builtin_amdgcn_mfma_f32_16x16x32_bf16(afr[0], bb.v, acc[0][nt], 0, 0, 0);
            acc[1][nt] = __builtin_amdgcn_mfma_f32_16x16x32_bf16(afr[1], bb.v, acc[1][nt], 0, 0, 0);
        }
    }

    // ---- b2 for this wave's 96 columns ----
    float gb2v[6];
    #pragma unroll
    for (int nt = 0; nt < 6; ++nt) gb2v[nt] = b2[n0g + nt * 16 + n15];

    __syncthreads();                          // all MFMA reads of bT complete

    // ---- epilogue via wave-private LDS w-tile bounce ----
    float* wl = ((float*)bT) + wave * WL_SZ;  // 16 x 97 f32, wave-private

    #pragma unroll
    for (int mi = 0; mi < 2; ++mi) {
        // produce: w[kc][n] = acc + b2   (kc = quad*4+r, n = nt*16+n15)
        #pragma unroll
        for (int nt = 0; nt < 6; ++nt)
            #pragma unroll
            for (int r = 0; r < 4; ++r)
                wl[(quad * 4 + r) * WL_ST + nt * 16 + n15] = acc[mi][nt][r] + gb2v[nt];
        // (compiler inserts lgkmcnt before dependent ds_read; wave-private)

        const int o = (wave * 2 + mi) * 128 + oc;
        const float* uo = unet + (size_t)o * 6144;
        float* ob = out + (size_t)o * 18432;

        // drain: per (kp, half) one (o,kc) 288-dword run; lanes L contiguous
        #pragma unroll
        for (int kp = 0; kp < 8; ++kp) {
            const int kc = kp * 2 + half;
            const float* wrow = wl + kc * WL_ST;
            const float* ub = uo + kc * 384 + icq * 96;
            float* os = ob + kc * 1152 + icq * 288;
            #pragma unroll
            for (int j = 0; j < 9; ++j) {
                const int d  = j * 32 + L;    // 0..287 within the run
                const int d3 = d / 3;         // = ic_rel*3 + kw  (w column)
                const int d9 = d / 9;         // = ic_rel
                const int l  = d - 3 * d3;    // = l
                os[d] = wrow[d3] * ub[d9 * 3 + l];
            }
        }
    }
}

// ---------------------------------------------------------------------------
extern "C" void kernel_launch(void* const* d_in, const int* in_sizes, int n_in,
                              void* d_out, int out_size, void* d_ws, size_t ws_size,
                              hipStream_t stream) {
    const float* Z       = (const float*)d_in[0];
    const float* z_bias  = (const float*)d_in[1];
    const float* unet_w  = (const float*)d_in[2];
    const float* unet_b  = (const float*)d_in[3];
    const float* pde     = (const float*)d_in[4];
    const float* W1      = (const float*)d_in[5];
    const float* U1      = (const float*)d_in[6];
    const float* b1      = (const float*)d_in[7];
    const float* W2      = (const float*)d_in[8];
    const float* b2      = (const float*)d_in[9];
    float* out = (float*)d_out;

    unsigned short* hiddenA = (unsigned short*)d_ws;   // 256*256 bf16 = 128 KB

    prep_kernel<<<256, 256, 0, stream>>>(Z, pde, W1, U1, b1, z_bias, unet_b,
                                         hiddenA, out + W2D_OUT);
    gemm_expand<<<512, 512, 0, stream>>>(hiddenA, W2, b2, unet_w, out);
}